// Round 11
// baseline (175.247 us; speedup 1.0000x reference)
//
#include <hip/hip_runtime.h>
#include <hip/hip_bf16.h>
#include <math.h>

#define D_MODEL 1024
#define NHEADS  16
#define DK      64
#define SEQ     2048
#define KDIM    1024

typedef __bf16 bf16x8 __attribute__((ext_vector_type(8)));
typedef short  s16x4  __attribute__((ext_vector_type(4)));
typedef float  f32x4  __attribute__((ext_vector_type(4)));

__device__ __forceinline__ void gload16(const void* g, void* l) {
    __builtin_amdgcn_global_load_lds(
        (const __attribute__((address_space(1))) void*)g,
        (__attribute__((address_space(3))) void*)l, 16, 0, 0);
}

__device__ __forceinline__ unsigned short f2bf(float f) {
    __hip_bfloat16 h = __float2bfloat16(f);
    return *(unsigned short*)&h;
}

// packed 2x f32 -> bf16x2 (low word = a)
__device__ __forceinline__ unsigned pk2bf(float a, float b) {
    __hip_bfloat162 h = __float22bfloat162_rn(make_float2(a, b));
    return *(unsigned*)&h;
}

// Q is pre-scaled by 1/sqrt(dk) * log2(e) so attention runs in exp2 domain.
#define QSCALE 0.18033688011112042f

// ---------------------------------------------------------------------------
// Kernel 0: cast x / qkv-weights / out-weights to bf16 workspace copies.
// ---------------------------------------------------------------------------
__global__ __launch_bounds__(256) void cast_kernel(
    const float* __restrict__ x,
    const float* __restrict__ qw,
    const float* __restrict__ kw,
    const float* __restrict__ vw,
    const float* __restrict__ wo,
    unsigned short* __restrict__ xb,     // [4096*1024]
    unsigned short* __restrict__ wqkv,   // [3072*1024]
    unsigned short* __restrict__ wob)    // [1024*1024]
{
    const size_t t = (size_t)blockIdx.x * 256 + threadIdx.x;  // float4 index
    const size_t X4 = 1048576;
    const size_t W4 = 262144;

    const float* src;
    unsigned short* dst;
    size_t o;
    if (t < X4)            { src = x;  dst = xb;             o = t; }
    else if (t < X4 + W4)  { src = qw; dst = wqkv;           o = t - X4; }
    else if (t < X4 + 2*W4){ src = kw; dst = wqkv + 1048576; o = t - X4 - W4; }
    else if (t < X4 + 3*W4){ src = vw; dst = wqkv + 2097152; o = t - X4 - 2*W4; }
    else                   { src = wo; dst = wob;            o = t - X4 - 3*W4; }

    float4 v = ((const float4*)src)[o];
    ushort4 r;
    r.x = f2bf(v.x); r.y = f2bf(v.y); r.z = f2bf(v.z); r.w = f2bf(v.w);
    ((ushort4*)dst)[o] = r;
}

// ---------------------------------------------------------------------------
// Kernel 1: QKV MFMA GEMM: C[M,3072] = A[M,K]*B[N,K]^T, bf16. m97 structure.
// Each block's 128 cols lie in ONE matrix: m=0 -> Q bf16 [bh,s,dk] (xQSCALE),
// m=1 -> K bf16 [bh,s,dk], m=2 -> V^T bf16 [bh,dk,s].
// ALL epilogues via 32 KB LDS transpose -> coalesced 16B stores.
// ---------------------------------------------------------------------------
__global__ __launch_bounds__(256) void mfma_gemm_qkv(
    const unsigned short* __restrict__ A,   // [M,1024] bf16
    const unsigned short* __restrict__ B,   // [N,1024] bf16
    unsigned short* __restrict__ Qb,
    unsigned short* __restrict__ Kb,
    unsigned short* __restrict__ Vtb)
{
    __shared__ __align__(16) unsigned short smem[16384];   // 32 KB
    unsigned short* As = smem;           // [128][32], 8 KB
    unsigned short* Bs = smem + 4096;    // [128][32], 8 KB

    const int tid  = threadIdx.x;
    const int wave = tid >> 6;
    const int lane = tid & 63;
    const int wr   = wave >> 1;
    const int wc   = wave & 1;
    const int quad = lane >> 4;
    const int l16  = lane & 15;

    const int rowBase = blockIdx.y * 128;
    const int colBase = blockIdx.x * 128;

    f32x4 acc[4][4];
    const f32x4 z = {0.f, 0.f, 0.f, 0.f};
#pragma unroll
    for (int i = 0; i < 4; ++i)
#pragma unroll
        for (int j = 0; j < 4; ++j) acc[i][j] = z;

    const int srow = lane >> 2;          // 0..15
    const int skof = (lane & 3) * 8;     // 0/8/16/24

    for (int k0 = 0; k0 < KDIM; k0 += 32) {
        __syncthreads();

        const unsigned short* ga =
            A + (size_t)(rowBase + wave * 32) * KDIM + k0;
        gload16(ga + (size_t)srow * KDIM + skof,        &As[(wave*32)    * 32]);
        gload16(ga + (size_t)(16 + srow) * KDIM + skof, &As[(wave*32+16) * 32]);

        const unsigned short* gb =
            B + (size_t)(colBase + wave * 32) * KDIM + k0;
        gload16(gb + (size_t)srow * KDIM + skof,        &Bs[(wave*32)    * 32]);
        gload16(gb + (size_t)(16 + srow) * KDIM + skof, &Bs[(wave*32+16) * 32]);

        __syncthreads();

        bf16x8 af[4], bfr[4];
#pragma unroll
        for (int t = 0; t < 4; ++t)
            af[t] = *(const bf16x8*)&As[(wr*64 + t*16 + l16) * 32 + quad*8];
#pragma unroll
        for (int t = 0; t < 4; ++t)
            bfr[t] = *(const bf16x8*)&Bs[(wc*64 + t*16 + l16) * 32 + quad*8];

#pragma unroll
        for (int tr = 0; tr < 4; ++tr)
#pragma unroll
            for (int tc = 0; tc < 4; ++tc)
                acc[tr][tc] = __builtin_amdgcn_mfma_f32_16x16x32_bf16(
                    af[tr], bfr[tc], acc[tr][tc], 0, 0, 0);
    }

    // C/D layout: col = lane&15, row = quad*4 + reg
    const int mat = colBase >> 10;       // uniform per block: 0=Q,1=K,2=V
    const int b   = rowBase >> 11;
    const int sblk = rowBase & (SEQ - 1);
    __syncthreads();                     // K-loop LDS reads done
    if (mat == 2) {
        // V^T: transpose via LDS. smem layout [128 kk][16 chunks of 8 s],
        // chunk position XOR-swizzled by (kk&15).
#pragma unroll
        for (int tr = 0; tr < 4; ++tr) {
#pragma unroll
            for (int tc = 0; tc < 4; ++tc) {
                const int col = wc*64 + tc*16 + l16;       // kk (local)
#pragma unroll
                for (int reg = 0; reg < 4; ++reg) {
                    const int row = wr*64 + tr*16 + quad*4 + reg;   // s (local)
                    const int chunk = (row >> 3) ^ (col & 15);
                    smem[col*128 + chunk*8 + (row & 7)] = f2bf(acc[tr][tc][reg]);
                }
            }
        }
        __syncthreads();
        const int h0 = (colBase & 1023) >> 6;
#pragma unroll
        for (int i = 0; i < 8; ++i) {
            const int g  = i*256 + tid;          // 0..2047 16B chunks
            const int kk = g >> 4;               // local col 0..127
            const int ci = g & 15;               // s-chunk
            const int chunk = ci ^ (kk & 15);
            uint4 v = *(uint4*)&smem[kk*128 + chunk*8];
            const int h  = h0 + (kk >> 6), dk = kk & 63;
            *(uint4*)(Vtb + ((size_t)(b*NHEADS + h)*DK + dk)*SEQ + sblk + ci*8) = v;
        }
    } else {
        // Q/K: LDS transpose -> coalesced 16B stores
        const float sc = (mat == 0) ? QSCALE : 1.0f;
#pragma unroll
        for (int tr = 0; tr < 4; ++tr) {
#pragma unroll
            for (int tc = 0; tc < 4; ++tc) {
                const int col   = wc*64 + tc*16 + l16;
                const int cbase = col >> 3, c7 = col & 7;
#pragma unroll
                for (int reg = 0; reg < 4; ++reg) {
                    const int row = wr*64 + tr*16 + quad*4 + reg;
                    const int chunk = cbase ^ (row & 15);
                    smem[row*128 + chunk*8 + c7] = f2bf(acc[tr][tc][reg] * sc);
                }
            }
        }
        __syncthreads();
        const int h0 = (colBase & 1023) >> 6;   // first of the 2 heads
        unsigned short* dstb = (mat == 0) ? Qb : Kb;
#pragma unroll
        for (int i = 0; i < 8; ++i) {
            const int g    = i*256 + tid;       // 0..2047 16B-chunks
            const int head = g >> 10;
            const int s    = (g >> 3) & 127;
            const int ci   = g & 7;
            const int chunk = (head*8 + ci) ^ (s & 15);
            uint4 v = *(uint4*)&smem[s*128 + chunk*8];
            *(uint4*)(dstb + ((size_t)(b*NHEADS + h0 + head)*SEQ + sblk + s)*DK
                           + ci*8) = v;
        }
    }
}

// ---------------------------------------------------------------------------
// Kernel 2: MFMA flash attention. Transposed formulation, exp2 domain, no
// running max, register-resident P. NEW: double-buffered K/V staging —
// prefetch for tile jt+1 is issued right after the barrier, so the
// vmcnt(0) drain before the NEXT barrier happens after a full compute
// phase instead of immediately (the R10 structure staged and immediately
// drained: ~1/3 of wall time was that stall). LDS 16 -> 32 KB.
// ---------------------------------------------------------------------------
__global__ __launch_bounds__(256, 2) void attn_mfma_kernel(
    const unsigned short* __restrict__ Qb,   // [bh, s, 64] bf16 (pre-scaled)
    const unsigned short* __restrict__ Kb,   // [bh, s, 64] bf16
    const unsigned short* __restrict__ Vtb,  // [bh, 64, s] bf16
    unsigned short* __restrict__ O)          // [b, s, 1024] bf16
{
    __shared__ unsigned short Ks[2][64 * 64];    // 2 x 8 KB
    __shared__ unsigned short Vs[2][64 * 64];    // 2 x 8 KB

    const int bh   = blockIdx.x;
    const int qt   = 31 - blockIdx.y;     // long (causal-heavy) tiles first
    const int wave = threadIdx.x >> 6;
    const int lane = threadIdx.x & 63;
    const int quad = lane >> 4;
    const int l16  = lane & 15;

    // Q fragment (B-operand of S^T = K.Q^T): row n = q
    const size_t qrow = (size_t)bh * SEQ + qt*64 + wave*16 + l16;
    bf16x8 aq0 = *(const bf16x8*)(Qb + qrow * DK + quad*8);
    bf16x8 aq1 = *(const bf16x8*)(Qb + qrow * DK + 32 + quad*8);

    f32x4 o_acc[4];
    const f32x4 z = {0.f, 0.f, 0.f, 0.f};
#pragma unroll
    for (int i = 0; i < 4; ++i) o_acc[i] = z;
    float lrow = 0.f;

    const int srow8  = lane >> 3;    // row within 8-row staging slab
    const int schunk = lane & 7;     // LDS 16B-chunk position
    const unsigned short* Kbase = Kb  + (size_t)bh * SEQ * DK;
    const unsigned short* Vbase = Vtb + (size_t)bh * DK * SEQ;

    const int ntiles = qt + 1;

    // prefetch tile 0 into buffer 0
#pragma unroll
    for (int n = 0; n < 2; ++n) {
        const int r = wave*16 + n*8 + srow8;          // r & 7 == srow8
        gload16(Kbase + (size_t)r * DK + (schunk ^ srow8) * 8,
                &Ks[0][(wave*16 + n*8) * 64]);
        gload16(Vbase + (size_t)r * SEQ + (schunk ^ srow8) * 8,
                &Vs[0][(wave*16 + n*8) * 64]);
    }

    int bsel = 0;
    for (int jt = 0; jt < ntiles; ++jt) {
        __syncthreads();   // own vmcnt drained -> tile jt (buf bsel) ready;
                           // all waves done reading buf bsel^1
        if (jt + 1 < ntiles) {
            const int j1 = (jt + 1) * 64;
#pragma unroll
            for (int n = 0; n < 2; ++n) {
                const int r = wave*16 + n*8 + srow8;
                gload16(Kbase + (size_t)(j1 + r) * DK + (schunk ^ srow8) * 8,
                        &Ks[bsel ^ 1][(wave*16 + n*8) * 64]);
                gload16(Vbase + (size_t)r * SEQ + j1 + (schunk ^ srow8) * 8,
                        &Vs[bsel ^ 1][(wave*16 + n*8) * 64]);
            }
        }

        const unsigned short* Kc = Ks[bsel];
        const unsigned short* Vc = Vs[bsel];

        // S^T = K.Q^T : A = K rows (m = key), B = Q rows (n = query)
        f32x4 st[4];
#pragma unroll
        for (int ct = 0; ct < 4; ++ct) {
            const int r = ct*16 + l16;               // key row
            bf16x8 k0 = *(const bf16x8*)&Kc[r*64 + ((quad     ^ (r&7)) * 8)];
            bf16x8 k1 = *(const bf16x8*)&Kc[r*64 + (((4+quad) ^ (r&7)) * 8)];
            f32x4 t = z;
            t = __builtin_amdgcn_mfma_f32_16x16x32_bf16(k0, aq0, t, 0, 0, 0);
            t = __builtin_amdgcn_mfma_f32_16x16x32_bf16(k1, aq1, t, 0, 0, 0);
            st[ct] = t;
        }

        // causal mask (diagonal tile only): key_local <= q_local
        if (jt == qt) {
#pragma unroll
            for (int ct = 0; ct < 4; ++ct)
#pragma unroll
                for (int reg = 0; reg < 4; ++reg) {
                    const int kl = ct*16 + quad*4 + reg;
                    const int ql = wave*16 + l16;
                    if (kl > ql) st[ct][reg] = -1e30f;  // exp2 -> 0
                }
        }

        // p = exp2(S) (no max subtraction); row sum across 4 quads
        float rs = 0.f;
#pragma unroll
        for (int ct = 0; ct < 4; ++ct)
#pragma unroll
            for (int reg = 0; reg < 4; ++reg) {
                float p = exp2f(st[ct][reg]);
                st[ct][reg] = p;
                rs += p;
            }
        rs += __shfl_xor(rs, 16);
        rs += __shfl_xor(rs, 32);
        lrow += rs;

        // pack P^T fragments in-register: st[ct] (query l16, keys quad*4+r)
        // is exactly B[n=l16][k=quad*4+j] of mfma_f32_16x16x16_bf16
        s16x4 pf[4];
#pragma unroll
        for (int ct = 0; ct < 4; ++ct) {
            union { unsigned u[2]; s16x4 s; } cv;
            cv.u[0] = pk2bf(st[ct][0], st[ct][1]);
            cv.u[1] = pk2bf(st[ct][2], st[ct][3]);
            pf[ct] = cv.s;
        }

        // O^T += V^T . P^T  via 16x16x16 (A = V^T rows: m = dk, k = keys)
#pragma unroll
        for (int ot = 0; ot < 4; ++ot) {
            const int r = ot*16 + l16;               // dk row
#pragma unroll
            for (int ct = 0; ct < 4; ++ct) {
                const int cix = ct*2 + (quad >> 1);  // 16B chunk of keys
                s16x4 vf = *(const s16x4*)&Vc[r*64 + ((cix ^ (r&7)) << 3)
                                              + (quad & 1) * 4];
                o_acc[ot] = __builtin_amdgcn_mfma_f32_16x16x16bf16_1k(
                    vf, pf[ct], o_acc[ot], 0, 0, 0);
            }
        }
        bsel ^= 1;
    }

    // epilogue: lane owns query l16, dk = ot*16 + quad*4 + reg
    const float inv = 1.f / lrow;
    const int b = bh >> 4, h = bh & 15;
    const int sg = qt*64 + wave*16 + l16;
    unsigned short* orow = O + ((size_t)(b * SEQ + sg)) * D_MODEL + h * DK;
#pragma unroll
    for (int ot = 0; ot < 4; ++ot) {
        uint2 pk;
        pk.x = pk2bf(o_acc[ot][0] * inv, o_acc[ot][1] * inv);
        pk.y = pk2bf(o_acc[ot][2] * inv, o_acc[ot][3] * inv);
        *(uint2*)(orow + ot*16 + quad*4) = pk;
    }
}

// ---------------------------------------------------------------------------
// Kernel 3: output projection GEMM, 64x128 tile (512 blocks = 2/CU).
// C fp32 [4096,1024] = AO[4096,1024] * WOB[1024,1024]^T.
// ---------------------------------------------------------------------------
__global__ __launch_bounds__(256) void mfma_gemm_out(
    const unsigned short* __restrict__ A,   // [4096,1024] bf16
    const unsigned short* __restrict__ B,   // [1024,1024] bf16
    float* __restrict__ C0)
{
    __shared__ __align__(16) unsigned short As[64 * 32];    // 4 KB
    __shared__ __align__(16) unsigned short Bs[128 * 32];   // 8 KB

    const int tid  = threadIdx.x;
    const int wave = tid >> 6;
    const int lane = tid & 63;
    const int wr   = wave & 1;         // row strip (32)
    const int wc   = wave >> 1;        // col strip (64)
    const int quad = lane >> 4;
    const int l16  = lane & 15;

    const int rowBase = blockIdx.y * 64;
    const int colBase = blockIdx.x * 128;

    f32x4 acc[2][4];
    const f32x4 z = {0.f, 0.f, 0.f, 0.f};
#pragma unroll
    for (int i = 0; i < 2; ++i)
#pragma unroll
        for (int j = 0; j < 4; ++j) acc[i][j] = z;

    const int srow = lane >> 2;          // 0..15
    const int skof = (lane & 3) * 8;     // 0/8/16/24

    for (int k0 = 0; k0 < KDIM; k0 += 32) {
        __syncthreads();

        const unsigned short* ga =
            A + (size_t)(rowBase + wave * 16) * KDIM + k0;
        gload16(ga + (size_t)srow * KDIM + skof, &As[(wave*16) * 32]);

        const unsigned short* gb =
            B + (size_t)(colBase + wave * 32) * KDIM + k0;
        gload16(gb + (size_t)srow * KDIM + skof,        &Bs[(wave*32)    * 32]);
        gload16(gb + (size_t)(16 + srow) * KDIM + skof, &Bs[(wave*32+16) * 32]);

        __syncthreads();

        bf16x8 af[2], bfr[4];
#pragma unroll
        for (int t = 0; t < 2; ++t)
            af[t] = *(const bf16x8*)&As[(wr*32 + t*16 + l16) * 32 + quad*8];
#pragma unroll
        for (int t = 0; t < 4; ++t)
            bfr[t] = *(const bf16x8*)&Bs[(wc*64 + t*16 + l16) * 32 + quad*8];

#pragma unroll
        for (int tr = 0; tr < 2; ++tr)
#pragma unroll
            for (int tc = 0; tc < 4; ++tc)
                acc[tr][tc] = __builtin_amdgcn_mfma_f32_16x16x32_bf16(
                    af[tr], bfr[tc], acc[tr][tc], 0, 0, 0);
    }

#pragma unroll
    for (int tr = 0; tr < 2; ++tr) {
#pragma unroll
        for (int tc = 0; tc < 4; ++tc) {
            const int grow0 = rowBase + wr*32 + tr*16 + quad*4;
            const int gcol  = colBase + wc*64 + tc*16 + l16;
#pragma unroll
            for (int reg = 0; reg < 4; ++reg)
                C0[(size_t)(grow0 + reg) * D_MODEL + gcol] = acc[tr][tc][reg];
        }
    }
}

extern "C" void kernel_launch(void* const* d_in, const int* in_sizes, int n_in,
                              void* d_out, int out_size, void* d_ws, size_t ws_size,
                              hipStream_t stream) {
    const float* x  = (const float*)d_in[0];
    const float* qw = (const float*)d_in[1];
    const float* kw = (const float*)d_in[2];
    const float* vw = (const float*)d_in[3];
    const float* wo = (const float*)d_in[4];
    float* out = (float*)d_out;

    // workspace (48 MB of the 64): all bf16
    //  [ 0, 8) Qb [bh,s,64]   [ 8,16) Kb   [16,24) Vt [bh,64,s]
    //  [24,32) AO [b,s,1024]  [32,40) XB   [40,46) WQKV  [46,48) WOB
    char* ws = (char*)d_ws;
    unsigned short* Qb   = (unsigned short*)(ws);
    unsigned short* Kb   = (unsigned short*)(ws + (size_t) 8*1024*1024);
    unsigned short* Vtb  = (unsigned short*)(ws + (size_t)16*1024*1024);
    unsigned short* AO   = (unsigned short*)(ws + (size_t)24*1024*1024);
    unsigned short* XB   = (unsigned short*)(ws + (size_t)32*1024*1024);
    unsigned short* WQKV = (unsigned short*)(ws + (size_t)40*1024*1024);
    unsigned short* WOB  = (unsigned short*)(ws + (size_t)46*1024*1024);

    cast_kernel<<<8192, 256, 0, stream>>>(x, qw, kw, vw, wo, XB, WQKV, WOB);

    dim3 g1(24, 32);             // N=3072/128, M=4096/128
    mfma_gemm_qkv<<<g1, 256, 0, stream>>>(XB, WQKV, Qb, Kb, Vtb);

    dim3 g2(32, 32);             // bh, 64-query tiles (y reversed in-kernel)
    attn_mfma_kernel<<<g2, 256, 0, stream>>>(Qb, Kb, Vtb, AO);

    dim3 g3(8, 64);              // N=1024/128, M=4096/64
    mfma_gemm_out<<<g3, 256, 0, stream>>>(AO, WOB, out);
}